// Round 13
// baseline (104.488 us; speedup 1.0000x reference)
//
#include <hip/hip_runtime.h>
#include <hip/hip_bf16.h>

typedef __bf16 bf16_t;
typedef __bf16 bf16x4 __attribute__((ext_vector_type(4)));
typedef __bf16 bf16x8 __attribute__((ext_vector_type(8)));
typedef float f32x4 __attribute__((ext_vector_type(4)));

#define M_TOT 8192
#define N_TOT 512
#define K_TOT 2048
#define E_TOT 512
#define NSEG_HALF 16      // 16 tiles of BK=64 per k-slice (K=2048 split x2)

__device__ __forceinline__ bf16x8 zero8() {
    bf16x8 v;
#pragma unroll
    for (int i = 0; i < 8; ++i) v[i] = (bf16_t)0.0f;
    return v;
}

// ---------------------------------------------------------------------------
// prep4 (identical to R12; correctness-proven):
//  blocks [0,256):   W2[k][n] -> W2f FRAGMENT-MAJOR bf16:
//    per (n_block 0..7, k_tile 0..31), 4096 bf16; chunk ci = c*256+nt*64+l
//    holds W2[k_tile*64 + (c*4+(l>>4))*8 + j][n_block*64 + nt*16 + (l&15)].
//    A wave's B-fragment read is ONE coalesced dwordx4 per (c,nt).
//  blocks [256,288): zb[m][0..8)=cos(theta[q])*cos(x[m,q]) (RX collapse);
//                    zb[m][8]=1; rest 0
//  blocks [288,296): W1p: permuted W1 rows + bias so h-MFMA C-output lands
//    exactly in main-MFMA A-fragment layout.
// ---------------------------------------------------------------------------
__global__ __launch_bounds__(256)
void prep4_kernel(const float* __restrict__ x,
                  const float* __restrict__ theta,
                  const float* __restrict__ W1,
                  const float* __restrict__ b1,
                  const float* __restrict__ W2,
                  bf16_t* __restrict__ W2f,
                  bf16_t* __restrict__ zb,
                  bf16_t* __restrict__ W1p)
{
    const int b = blockIdx.x;
    if (b < 256) {
        __shared__ bf16_t T[64][66];
        const int k0 = (b >> 3) * 64;
        const int n0 = (b & 7) * 64;
        const int kl = threadIdx.x >> 4;
        const int n4 = threadIdx.x & 15;
#pragma unroll
        for (int i = 0; i < 4; ++i) {
            int k = kl + i * 16;
            float4 v = *(const float4*)(W2 + (size_t)(k0 + k) * N_TOT + n0 + n4 * 4);
            T[n4 * 4 + 0][k] = (bf16_t)v.x;
            T[n4 * 4 + 1][k] = (bf16_t)v.y;
            T[n4 * 4 + 2][k] = (bf16_t)v.z;
            T[n4 * 4 + 3][k] = (bf16_t)v.w;
        }
        __syncthreads();
        const size_t base = (size_t)((b & 7) * 32 + (b >> 3)) * 4096;
#pragma unroll
        for (int i = 0; i < 2; ++i) {
            int ci = threadIdx.x + i * 256;        // chunk 0..511
            int c  = ci >> 8;
            int nt = (ci >> 6) & 3;
            int l  = ci & 63;
            int nl = nt * 16 + (l & 15);
            int kk = (c * 4 + (l >> 4)) * 8;
            bf16x8 v;
#pragma unroll
            for (int j = 0; j < 8; ++j) v[j] = T[nl][kk + j];
            *(bf16x8*)(W2f + base + (size_t)ci * 8) = v;
        }
    } else if (b < 288) {
        const int m = (b - 256) * 256 + threadIdx.x;
        float4 x0 = *(const float4*)(x + (size_t)m * E_TOT);
        float4 x1 = *(const float4*)(x + (size_t)m * E_TOT + 4);
        float xs[8] = {x0.x, x0.y, x0.z, x0.w, x1.x, x1.y, x1.z, x1.w};
        bf16x8 lo;
#pragma unroll
        for (int q = 0; q < 8; ++q)
            lo[q] = (bf16_t)(__builtin_cosf(theta[q]) * __builtin_cosf(xs[q]));
        bf16x8 hi = zero8();
        hi[0] = (bf16_t)1.0f;                  // bias lane at k=8
        *(bf16x8*)(zb + (size_t)m * 16)     = lo;
        *(bf16x8*)(zb + (size_t)m * 16 + 8) = hi;
    } else {
        const int d  = (b - 288) * 256 + threadIdx.x;    // 0..2047
        const int c  = d >> 5;
        const int dd = d & 31;
        const int p  = dd >> 4;
        const int rr = dd & 15;
        const int f  = c * 32 + ((rr >> 2) << 3) + (p << 2) + (rr & 3);
        bf16x8 lo;
#pragma unroll
        for (int q = 0; q < 8; ++q)
            lo[q] = (bf16_t)W1[(size_t)q * K_TOT + f];
        bf16x8 hi = zero8();
        hi[0] = (bf16_t)b1[f];                 // bias at k=8
        *(bf16x8*)(W1p + (size_t)d * 16)     = lo;
        *(bf16x8*)(W1p + (size_t)d * 16 + 8) = hi;
    }
}

// W1p frags for one 64-k tile (2 chunks x 2 perm-halves); lanes lq<2 real.
__device__ __forceinline__ void load_wf(const bf16_t* __restrict__ W1p, int k0,
                                        int l15, int lq, bf16x8 wf[4]) {
#pragma unroll
    for (int i = 0; i < 4; ++i) wf[i] = zero8();
    if (lq < 2) {
        const int base = (k0 >> 5) * 2;
#pragma unroll
        for (int i = 0; i < 4; ++i)
            wf[i] = *(const bf16x8*)(W1p + (size_t)((base + i) * 16 + l15) * 16 + lq * 8);
    }
}

// B-fragments for one 64-k tile: 8 coalesced dwordx4 from fragment-major W2f
// (L2-resident). Same base per tile, immediate offsets.
__device__ __forceinline__ void load_bfr(const bf16_t* __restrict__ tb,
                                         int l, bf16x8 bfr[2][4]) {
#pragma unroll
    for (int c = 0; c < 2; ++c)
#pragma unroll
        for (int nt = 0; nt < 4; ++nt)
            bfr[c][nt] = *(const bf16x8*)(tb + (size_t)(c * 256 + nt * 64 + l) * 8);
}

// one 64-k tile from PRE-LOADED registers: h (layout-matched MFMA) + mains.
// Operand values and MFMA order per acc register identical to R5/R9/R12 ->
// bit-identical numerics.
__device__ __forceinline__ void tile_compute(const bf16x8 wf[4],
                                             const bf16x8 bfr[2][4],
                                             const bf16x8 zfrag[2],
                                             f32x4 acc[2][4]) {
    bf16x8 af[2][2];
#pragma unroll
    for (int mt = 0; mt < 2; ++mt)
#pragma unroll
        for (int c = 0; c < 2; ++c) {
            f32x4 h0 = (f32x4){0.f, 0.f, 0.f, 0.f};
            f32x4 h1 = (f32x4){0.f, 0.f, 0.f, 0.f};
            h0 = __builtin_amdgcn_mfma_f32_16x16x32_bf16(wf[c * 2 + 0], zfrag[mt], h0, 0, 0, 0);
            h1 = __builtin_amdgcn_mfma_f32_16x16x32_bf16(wf[c * 2 + 1], zfrag[mt], h1, 0, 0, 0);
            bf16x8 a;
#pragma unroll
            for (int r = 0; r < 4; ++r) {
                a[r]     = (bf16_t)fmaxf(h0[r], 0.f);
                a[r + 4] = (bf16_t)fmaxf(h1[r], 0.f);
            }
            af[mt][c] = a;
        }

#pragma unroll
    for (int c = 0; c < 2; ++c)
#pragma unroll
        for (int mt = 0; mt < 2; ++mt)
#pragma unroll
            for (int nt = 0; nt < 4; ++nt)
                acc[mt][nt] = __builtin_amdgcn_mfma_f32_16x16x32_bf16(
                    af[mt][c], bfr[c][nt], acc[mt][nt], 0, 0, 0);
}

// ---------------------------------------------------------------------------
// Fused GEMM: out = relu(z@W1+b1) @ W2 + b2
// Block 64m x 64n, 256 thr = 4 waves = 2 m-slots (32m each) x 2 K-SLICES.
// No LDS / no barriers in the K-loop (R12); LDS only for split-K combine.
//
// R13 -- 2-DEEP REGISTER PREFETCH (the round's variable):
// R12 removed the barriers but kept each tile's loads immediately before
// their use, so every tile exposed the full L2 latency chain
// {12 loads -> h-MFMA -> VALU -> mains} (~550+ cyc) -- consistent with
// wall ~72k cyc/CU vs only ~11k of pipe work. Now tile s+1's bfr+wf loads
// are issued BEFORE tile s's compute (manual 2x unroll, named A/B register
// sets, static indexing): the wait before tile s+1's mains leaves the
// newer prefetch outstanding, so each wave self-hides a full tile of L2
// latency. Costs ~+48 VGPR -> __launch_bounds__(256,3) (12 waves/CU,
// proven-flat occupancy range). Numerics bit-identical.
// ---------------------------------------------------------------------------
__global__ __launch_bounds__(256, 3)
void ffq_gemm_kernel(const bf16_t* __restrict__ zb,    // [8192][16]
                     const bf16_t* __restrict__ W1p,   // [2048][16] permuted
                     const bf16_t* __restrict__ W2f,   // fragment-major
                     const float* __restrict__ b2,
                     float* __restrict__ out)          // [8192][512]
{
    __shared__ float F[4096];             // split-K combine scratch (16KB)

    const int t  = threadIdx.x;           // 0..255
    const int w  = t >> 6, l = t & 63;
    const int ks = w >> 1;                // k-slice 0/1
    const int wl = w & 1;                 // m-slot of 32 rows
    const int m_base = blockIdx.y * 64;
    const int n_blk  = blockIdx.x;
    const int n_base = n_blk * 64;
    const int l15 = l & 15, lq = l >> 4;
    const int k_base = ks * 1024;

    // persistent z^T B-frags for this wave's two 16-row m-tiles
    bf16x8 zfrag[2];
#pragma unroll
    for (int mt = 0; mt < 2; ++mt) {
        zfrag[mt] = zero8();
        if (lq < 2)
            zfrag[mt] = *(const bf16x8*)(zb + (size_t)(m_base + wl * 32 + mt * 16 + l15) * 16 + lq * 8);
    }

    f32x4 acc[2][4];
#pragma unroll
    for (int mt = 0; mt < 2; ++mt)
#pragma unroll
        for (int nt = 0; nt < 4; ++nt)
            acc[mt][nt] = (f32x4){0.f, 0.f, 0.f, 0.f};

    // this slice's first fragment-major tile (tiles contiguous in k)
    const bf16_t* tb = W2f + (size_t)(n_blk * 32 + ks * 16) * 4096;

    // prologue: load tile 0's operands into set A
    bf16x8 wfA[4], wfB[4], bfrA[2][4], bfrB[2][4];
    load_wf(W1p, k_base, l15, lq, wfA);
    load_bfr(tb, l, bfrA);

    // manual 2x unroll: even tile consumes A (prefetches B), odd consumes B
    // (prefetches A). All indices static -> registers, no scratch (rule #20).
    for (int sp = 0; sp < NSEG_HALF; sp += 2) {
        // ---- tile sp (set A); prefetch sp+1 (set B) ----
        load_wf(W1p, k_base + (sp + 1) * 64, l15, lq, wfB);
        load_bfr(tb + (size_t)(sp + 1) * 4096, l, bfrB);
        tile_compute(wfA, bfrA, zfrag, acc);

        // ---- tile sp+1 (set B); prefetch sp+2 (set A) ----
        if (sp + 2 < NSEG_HALF) {
            load_wf(W1p, k_base + (sp + 2) * 64, l15, lq, wfA);
            load_bfr(tb + (size_t)(sp + 2) * 4096, l, bfrA);
        }
        tile_compute(wfB, bfrB, zfrag, acc);
    }

    // ---- split-K combine through LDS ----
    __syncthreads();
    if (ks == 1) {
#pragma unroll
        for (int mt = 0; mt < 2; ++mt)
#pragma unroll
            for (int nt = 0; nt < 4; ++nt) {
                int idx = ((wl * 2 + mt) * 4 + nt) * 64 + l;   // lane-contig 16B
                *(f32x4*)(F + (size_t)idx * 4) = acc[mt][nt];
            }
    }
    __syncthreads();
    if (ks == 0) {
        // ---- epilogue: C/D layout col=lane&15, row=(lane>>4)*4+r ----
#pragma unroll
        for (int nt = 0; nt < 4; ++nt) {
            int col = n_base + nt * 16 + l15;
            float bias = b2[col];
#pragma unroll
            for (int mt = 0; mt < 2; ++mt) {
                int idx = ((wl * 2 + mt) * 4 + nt) * 64 + l;
                f32x4 part = *(const f32x4*)(F + (size_t)idx * 4);
#pragma unroll
                for (int r = 0; r < 4; ++r) {
                    int row = m_base + wl * 32 + mt * 16 + lq * 4 + r;
                    out[(size_t)row * N_TOT + col] = acc[mt][nt][r] + part[r] + bias;
                }
            }
        }
    }
}

extern "C" void kernel_launch(void* const* d_in, const int* in_sizes, int n_in,
                              void* d_out, int out_size, void* d_ws, size_t ws_size,
                              hipStream_t stream) {
    const float* x     = (const float*)d_in[0];
    const float* theta = (const float*)d_in[1];
    const float* W1    = (const float*)d_in[2];
    const float* b1    = (const float*)d_in[3];
    const float* W2    = (const float*)d_in[4];
    const float* b2    = (const float*)d_in[5];
    float* out = (float*)d_out;

    // ws: [0,2MB) W2f ; [2MB,2.25MB) zb[8192][16] ; then W1p[2048][16]
    const size_t W2F_BYTES = (size_t)N_TOT * K_TOT * sizeof(bf16_t);  // 2 MB
    const size_t ZB_BYTES  = (size_t)M_TOT * 16 * sizeof(bf16_t);     // 256 KB

    bf16_t* W2f = (bf16_t*)d_ws;
    bf16_t* zb  = (bf16_t*)((char*)d_ws + W2F_BYTES);
    bf16_t* W1p = (bf16_t*)((char*)d_ws + W2F_BYTES + ZB_BYTES);

    prep4_kernel<<<296, 256, 0, stream>>>(x, theta, W1, b1, W2, W2f, zb, W1p);

    dim3 grid(N_TOT / 64, M_TOT / 64);    // (8, 128) = 1024 blocks
    ffq_gemm_kernel<<<grid, 256, 0, stream>>>(zb, W1p, W2f, b2, out);
}

// Round 14
// 103.875 us; speedup vs baseline: 1.0059x; 1.0059x over previous
//
#include <hip/hip_runtime.h>
#include <hip/hip_bf16.h>

typedef __bf16 bf16_t;
typedef __bf16 bf16x4 __attribute__((ext_vector_type(4)));
typedef __bf16 bf16x8 __attribute__((ext_vector_type(8)));
typedef float f32x4 __attribute__((ext_vector_type(4)));

#define M_TOT 8192
#define N_TOT 512
#define K_TOT 2048
#define E_TOT 512
#define NSEG_HALF 8       // 8 segments of BK=128 per k-slice (K=2048 split x2)

__device__ __forceinline__ bf16x8 zero8() {
    bf16x8 v;
#pragma unroll
    for (int i = 0; i < 8; ++i) v[i] = (bf16_t)0.0f;
    return v;
}

// ---------------------------------------------------------------------------
// prep4 (correctness-proven):
//  blocks [0,256):   LDS-tiled transpose W2[k][n] -> W2t[n][k] bf16
//  blocks [256,288): zb[m][0..8)=cos(theta[q])*cos(x[m,q]) (RX collapse:
//                    |a2|^2-|b2|^2 = cos(theta)*cos(x)); zb[m][8]=1; rest 0
//  blocks [288,296): W1p: permuted W1 rows + bias so h-MFMA C-output lands
//    exactly in main-MFMA A-fragment layout.
//    Row d=(c*2+p)*16+rr holds f = c*32+(rr>>2)*8+p*4+(rr&3).
// ---------------------------------------------------------------------------
__global__ __launch_bounds__(256)
void prep4_kernel(const float* __restrict__ x,
                  const float* __restrict__ theta,
                  const float* __restrict__ W1,
                  const float* __restrict__ b1,
                  const float* __restrict__ W2,
                  bf16_t* __restrict__ W2t,
                  bf16_t* __restrict__ zb,
                  bf16_t* __restrict__ W1p)
{
    const int b = blockIdx.x;
    if (b < 256) {
        __shared__ bf16_t T[64][66];
        const int k0 = (b >> 3) * 64;
        const int n0 = (b & 7) * 64;
        const int kl = threadIdx.x >> 4;
        const int n4 = threadIdx.x & 15;
#pragma unroll
        for (int i = 0; i < 4; ++i) {
            int k = kl + i * 16;
            float4 v = *(const float4*)(W2 + (size_t)(k0 + k) * N_TOT + n0 + n4 * 4);
            T[n4 * 4 + 0][k] = (bf16_t)v.x;
            T[n4 * 4 + 1][k] = (bf16_t)v.y;
            T[n4 * 4 + 2][k] = (bf16_t)v.z;
            T[n4 * 4 + 3][k] = (bf16_t)v.w;
        }
        __syncthreads();
        const int nl = threadIdx.x >> 4;
        const int k4 = threadIdx.x & 15;
#pragma unroll
        for (int i = 0; i < 4; ++i) {
            int n = nl + i * 16;
            bf16x4 v;
            v[0] = T[n][k4 * 4 + 0];
            v[1] = T[n][k4 * 4 + 1];
            v[2] = T[n][k4 * 4 + 2];
            v[3] = T[n][k4 * 4 + 3];
            *(bf16x4*)(W2t + (size_t)(n0 + n) * K_TOT + k0 + k4 * 4) = v;
        }
    } else if (b < 288) {
        const int m = (b - 256) * 256 + threadIdx.x;
        float4 x0 = *(const float4*)(x + (size_t)m * E_TOT);
        float4 x1 = *(const float4*)(x + (size_t)m * E_TOT + 4);
        float xs[8] = {x0.x, x0.y, x0.z, x0.w, x1.x, x1.y, x1.z, x1.w};
        bf16x8 lo;
#pragma unroll
        for (int q = 0; q < 8; ++q)
            lo[q] = (bf16_t)(__builtin_cosf(theta[q]) * __builtin_cosf(xs[q]));
        bf16x8 hi = zero8();
        hi[0] = (bf16_t)1.0f;                  // bias lane at k=8
        *(bf16x8*)(zb + (size_t)m * 16)     = lo;
        *(bf16x8*)(zb + (size_t)m * 16 + 8) = hi;
    } else {
        const int d  = (b - 288) * 256 + threadIdx.x;    // 0..2047
        const int c  = d >> 5;
        const int dd = d & 31;
        const int p  = dd >> 4;
        const int rr = dd & 15;
        const int f  = c * 32 + ((rr >> 2) << 3) + (p << 2) + (rr & 3);
        bf16x8 lo;
#pragma unroll
        for (int q = 0; q < 8; ++q)
            lo[q] = (bf16_t)W1[(size_t)q * K_TOT + f];
        bf16x8 hi = zero8();
        hi[0] = (bf16_t)b1[f];                 // bias at k=8
        *(bf16x8*)(W1p + (size_t)d * 16)     = lo;
        *(bf16x8*)(W1p + (size_t)d * 16 + 8) = hi;
    }
}

// ---------------------------------------------------------------------------
// helpers (512-thread block = 8 waves: 4 m-slots x 2 k-slices;
//          block tile 128m x 64n, per-slice segment BK=128)
// ---------------------------------------------------------------------------
// B segment: 64n x 128k bf16 = 16KB, as two 64x64 k-tiles. LDS byte layout is
// LINEAR in s (byte = s*16, s=0..1023): tile=s>>9, n=(s>>3)&63, seg=s&7.
// The XOR swizzle (slot seg holds global k-chunk g=seg^(n&7)) is applied on
// the GLOBAL source address, LDS dest stays linear -> global_load_lds legal
// (wave-uniform base + lane*16); swizzled ds_read side unchanged.
// Staged by the k-slice's own 256 threads (4 waves x 4 slots).
__device__ __forceinline__ void stage_B(const bf16_t* __restrict__ W2t,
                                        bf16_t* dst_buf, int n_base, int k0,
                                        int wl, int l) {
#pragma unroll
    for (int j = 0; j < 4; ++j) {
        int s    = wl * 64 + l + j * 256;  // this lane's 16B slot (0..1023)
        int tile = s >> 9;
        int n    = (s >> 3) & 63;
        int g    = (s & 7) ^ (n & 7);
        const bf16_t* src = W2t + (size_t)(n_base + n) * K_TOT
                            + k0 + tile * 64 + g * 8;
        // wave-uniform LDS base for (wl,j); HW adds lane*16 -> byte s*16
        bf16_t* ldst = dst_buf + (size_t)(wl * 64 + j * 256) * 8;
        __builtin_amdgcn_global_load_lds(
            (const __attribute__((address_space(1))) unsigned int*)src,
            (__attribute__((address_space(3))) unsigned int*)ldst,
            16, 0, 0);
    }
}

// W1p frags for one 64-k tile (2 chunks x 2 perm-halves); lanes lq<2 real.
// k0 is the ABSOLUTE k offset (works for either k-slice).
__device__ __forceinline__ void load_wf(const bf16_t* __restrict__ W1p, int k0,
                                        int l15, int lq, bf16x8 wf[4]) {
#pragma unroll
    for (int i = 0; i < 4; ++i) wf[i] = zero8();
    if (lq < 2) {
        const int base = (k0 >> 5) * 2;
#pragma unroll
        for (int i = 0; i < 4; ++i)
            wf[i] = *(const bf16x8*)(W1p + (size_t)((base + i) * 16 + l15) * 16 + lq * 8);
    }
}

// one 64-k tile: B frags from LDS, h in registers (layout-matched MFMA), mains.
// wave tile 32m x 64n: each bfr feeds BOTH mt sub-tiles (low LDS bytes/FLOP).
// MFMA order per acc register identical across all proven variants ->
// bit-identical numerics.
__device__ __forceinline__ void compute_tile(const bf16_t* Bb, const bf16x8 wf[4],
                                             const bf16x8 zfrag[2],
                                             int l15, int lq,
                                             f32x4 acc[2][4]) {
    bf16x8 bfr[2][4];
#pragma unroll
    for (int c = 0; c < 2; ++c)
#pragma unroll
        for (int nt = 0; nt < 4; ++nt) {
            int r = nt * 16 + l15;
            int s = (c * 4 + lq) ^ (r & 7);
            bfr[c][nt] = *(const bf16x8*)(Bb + r * 64 + s * 8);
        }

    bf16x8 af[2][2];
#pragma unroll
    for (int mt = 0; mt < 2; ++mt)
#pragma unroll
        for (int c = 0; c < 2; ++c) {
            f32x4 h0 = (f32x4){0.f, 0.f, 0.f, 0.f};
            f32x4 h1 = (f32x4){0.f, 0.f, 0.f, 0.f};
            h0 = __builtin_amdgcn_mfma_f32_16x16x32_bf16(wf[c * 2 + 0], zfrag[mt], h0, 0, 0, 0);
            h1 = __builtin_amdgcn_mfma_f32_16x16x32_bf16(wf[c * 2 + 1], zfrag[mt], h1, 0, 0, 0);
            bf16x8 a;
#pragma unroll
            for (int r = 0; r < 4; ++r) {
                a[r]     = (bf16_t)fmaxf(h0[r], 0.f);
                a[r + 4] = (bf16_t)fmaxf(h1[r], 0.f);
            }
            af[mt][c] = a;
        }

#pragma unroll
    for (int c = 0; c < 2; ++c)
#pragma unroll
        for (int mt = 0; mt < 2; ++mt)
#pragma unroll
            for (int nt = 0; nt < 4; ++nt)
                acc[mt][nt] = __builtin_amdgcn_mfma_f32_16x16x32_bf16(
                    af[mt][c], bfr[c][nt], acc[mt][nt], 0, 0, 0);
}

// ---------------------------------------------------------------------------
// Fused GEMM: out = relu(z@W1+b1) @ W2 + b2   [R5 -- best measured: 102.45us]
// Block 128m x 64n, 512 thr = 8 waves = 4 m-slots (32m each) x 2 K-SLICES.
// Split-K x2 inside the block: slice ks handles k in [ks*1024,(ks+1)*1024),
// each with its own independent double-buffered 8-segment pipeline
// (LDS 2 slices x 2 bufs x 16KB = 64KB/block). Final combine through LDS
// (slice1 dumps f32 partials, slice0 adds + bias + store) -- deterministic.
// Grid (8,64)=512 blocks = 2 blocks/CU -> 16 waves/CU (4/SIMD).
// B staging via global_load_lds width=16 (async direct-to-LDS).
//
// SESSION VERDICT (R2-R13): GEMM time ~30-33us ( ~860 TF MFMA-issue ) is
// invariant to occupancy (8/12/16 w/CU), LDS bytes, staging mechanism
// (incl. NO staging at all, R12), barrier structure (incl. NO barriers,
// R12), VMEM issue order, h-chain overlap, and register prefetch -- the
// documented ~900TF ceiling of plain-HIP non-8-phase GEMM structures.
// The 8-phase escape needs a 256-block 8-wave grid and cannot map to
// N=512 (64-256 blocks -> <=1 block/CU; the 128^2+8phase quadrant is NULL
// per learn_hip m232). Remaining total is harness-fixed (~44us ws poison
// fill + ~5us prep + launch gaps).
// ---------------------------------------------------------------------------
__global__ __launch_bounds__(512, 4)
void ffq_gemm_kernel(const bf16_t* __restrict__ zb,    // [8192][16]
                     const bf16_t* __restrict__ W1p,   // [2048][16] permuted
                     const bf16_t* __restrict__ W2t,   // [512][2048]
                     const float* __restrict__ b2,
                     float* __restrict__ out)          // [8192][512]
{
    __shared__ bf16_t Blds[2][2][2 * 64 * 64];  // [kslice][buf][two 64x64 tiles]

    const int t  = threadIdx.x;           // 0..511
    const int w  = t >> 6, l = t & 63;
    const int ks = w >> 2;                // k-slice 0/1
    const int wl = w & 3;                 // m-slot of 32 rows
    const int m_base = blockIdx.y * 128;
    const int n_base = blockIdx.x * 64;
    const int l15 = l & 15, lq = l >> 4;
    const int k_base = ks * 1024;

    // persistent z^T B-frags for this wave's two 16-row m-tiles
    bf16x8 zfrag[2];
#pragma unroll
    for (int mt = 0; mt < 2; ++mt) {
        zfrag[mt] = zero8();
        if (lq < 2)
            zfrag[mt] = *(const bf16x8*)(zb + (size_t)(m_base + wl * 32 + mt * 16 + l15) * 16 + lq * 8);
    }

    f32x4 acc[2][4];
#pragma unroll
    for (int mt = 0; mt < 2; ++mt)
#pragma unroll
        for (int nt = 0; nt < 4; ++nt)
            acc[mt][nt] = (f32x4){0.f, 0.f, 0.f, 0.f};

    // prologue: this slice's segment 0 -> buf0 (async; first barrier drains)
    stage_B(W2t, Blds[ks][0], n_base, k_base, wl, l);

    for (int s = 0; s < NSEG_HALF; ++s) {
        const int cur = s & 1;
        __syncthreads();                   // vmcnt(0) drain + publish buf[cur]
        if (s + 1 < NSEG_HALF)
            stage_B(W2t, Blds[ks][1 - cur], n_base, k_base + (s + 1) * 128, wl, l);

#pragma unroll
        for (int tt = 0; tt < 2; ++tt) {
            bf16x8 wf[4];
            load_wf(W1p, k_base + s * 128 + tt * 64, l15, lq, wf);
            compute_tile(Blds[ks][cur] + tt * 4096, wf, zfrag, l15, lq, acc);
        }
    }

    // ---- split-K combine through LDS (reuse Blds as f32 scratch) ----
    __syncthreads();                       // all LDS reads of B done
    float* F = (float*)&Blds[0][0][0];     // 32KB needed, 64KB available
    if (ks == 1) {
#pragma unroll
        for (int mt = 0; mt < 2; ++mt)
#pragma unroll
            for (int nt = 0; nt < 4; ++nt) {
                int idx = ((wl * 2 + mt) * 4 + nt) * 64 + l;   // lane-contig 16B
                *(f32x4*)(F + (size_t)idx * 4) = acc[mt][nt];
            }
    }
    __syncthreads();
    if (ks == 0) {
        // ---- epilogue: C/D layout col=lane&15, row=(lane>>4)*4+r ----
#pragma unroll
        for (int nt = 0; nt < 4; ++nt) {
            int col = n_base + nt * 16 + l15;
            float bias = b2[col];
#pragma unroll
            for (int mt = 0; mt < 2; ++mt) {
                int idx = ((wl * 2 + mt) * 4 + nt) * 64 + l;
                f32x4 part = *(const f32x4*)(F + (size_t)idx * 4);
#pragma unroll
                for (int r = 0; r < 4; ++r) {
                    int row = m_base + wl * 32 + mt * 16 + lq * 4 + r;
                    out[(size_t)row * N_TOT + col] = acc[mt][nt][r] + part[r] + bias;
                }
            }
        }
    }
}

extern "C" void kernel_launch(void* const* d_in, const int* in_sizes, int n_in,
                              void* d_out, int out_size, void* d_ws, size_t ws_size,
                              hipStream_t stream) {
    const float* x     = (const float*)d_in[0];
    const float* theta = (const float*)d_in[1];
    const float* W1    = (const float*)d_in[2];
    const float* b1    = (const float*)d_in[3];
    const float* W2    = (const float*)d_in[4];
    const float* b2    = (const float*)d_in[5];
    float* out = (float*)d_out;

    // ws: [0,2MB) W2t ; [2MB,2.25MB) zb[8192][16] ; then W1p[2048][16]
    const size_t W2T_BYTES = (size_t)N_TOT * K_TOT * sizeof(bf16_t);  // 2 MB
    const size_t ZB_BYTES  = (size_t)M_TOT * 16 * sizeof(bf16_t);     // 256 KB

    bf16_t* W2t = (bf16_t*)d_ws;
    bf16_t* zb  = (bf16_t*)((char*)d_ws + W2T_BYTES);
    bf16_t* W1p = (bf16_t*)((char*)d_ws + W2T_BYTES + ZB_BYTES);

    prep4_kernel<<<296, 256, 0, stream>>>(x, theta, W1, b1, W2, W2t, zb, W1p);

    dim3 grid(N_TOT / 64, M_TOT / 128);   // (8, 64) = 512 blocks, 2/CU
    ffq_gemm_kernel<<<grid, 512, 0, stream>>>(zb, W1p, W2t, b2, out);
}